// Round 4
// baseline (118.252 us; speedup 1.0000x reference)
//
#include <hip/hip_runtime.h>

// ContrastiveQueueLoss: V (2,256,128) f32, L (256,128) f32, queue (65536,128) f32
// loss = -(1/256) * sum_{m<512} ( pos[m] - log( Spos[j(m)] + Sq[m] ) )

typedef float  float4v __attribute__((ext_vector_type(4)));
typedef short  short8  __attribute__((ext_vector_type(8)));

#define AS1 __attribute__((address_space(1)))
#define AS3 __attribute__((address_space(3)))

__device__ __forceinline__ unsigned short f2bf(float f) {
    union { float f; unsigned u; } v; v.f = f;
    unsigned r = v.u + 0x7FFFu + ((v.u >> 16) & 1u);   // RNE (inputs finite)
    return (unsigned short)(r >> 16);
}

// ======================================================= fast path =========

// 2048 blocks x 256. Converts queue->bf16 (qbf) and V->bf16 (abf); blocks
// 64..127 also compute pos[512].
__global__ __launch_bounds__(256) void convert_prep_kernel(
        const float* __restrict__ V, const float* __restrict__ L,
        const float* __restrict__ Qf,
        unsigned short* __restrict__ qbf, unsigned short* __restrict__ abf,
        float* __restrict__ pos) {
    const int tid = threadIdx.x;
    const int gt  = blockIdx.x * 256 + tid;
    const float4* q4 = (const float4*)Qf;
    uint2* qo = (uint2*)qbf;
    #pragma unroll
    for (int i = 0; i < 4; ++i) {                 // 8.39M floats total
        const int g = i * 524288 + gt;
        const float4 q = q4[g];
        uint2 p;
        p.x = (unsigned)f2bf(q.x) | ((unsigned)f2bf(q.y) << 16);
        p.y = (unsigned)f2bf(q.z) | ((unsigned)f2bf(q.w) << 16);
        qo[g] = p;
    }
    if (blockIdx.x < 64) {                        // V: 16384 float4s
        const float4 v = ((const float4*)V)[gt];
        uint2 p;
        p.x = (unsigned)f2bf(v.x) | ((unsigned)f2bf(v.y) << 16);
        p.y = (unsigned)f2bf(v.z) | ((unsigned)f2bf(v.w) << 16);
        ((uint2*)abf)[gt] = p;
    } else if (blockIdx.x < 128) {                // pos
        const int blk  = blockIdx.x - 64;
        const int w    = tid >> 6;
        const int lane = tid & 63;
        #pragma unroll
        for (int i = 0; i < 2; ++i) {
            const int r = blk * 8 + w * 2 + i;    // row in [0,512)
            const int b = r & 255;
            const float2 v = *reinterpret_cast<const float2*>(V + r * 128 + lane * 2);
            const float2 l = *reinterpret_cast<const float2*>(L + b * 128 + lane * 2);
            float p = v.x * l.x + v.y * l.y;
            #pragma unroll
            for (int off = 32; off; off >>= 1) p += __shfl_xor(p, off);
            if (lane == 0) pos[r] = 10.0f * p;
        }
    }
}

// 512 blocks x 256 threads. mt = bid>>8 (256 M rows), ng = bid&255 (256 queue
// rows = 4 tiles of 64). Wave keeps its 64x128 A-slice in registers; LDS holds
// double-buffered 64x128 B tiles streamed via global_load_lds with raw
// s_barrier + manual vmcnt. NO atomics: block writes 256 partial row sums to
// gbuf[row*256 + ng]; finalize reduces.
__global__ __launch_bounds__(256, 2) void gemm_exp_kernel(
        const unsigned short* __restrict__ abf,
        const unsigned short* __restrict__ qbf,
        float* __restrict__ gbuf) {
    __shared__ unsigned short Bs[2][64 * 128];    // 32 KB
    __shared__ float rowsum[256];

    const int tid  = threadIdx.x;
    const int bid  = blockIdx.x;
    const int mt   = bid >> 8;
    const int ng   = bid & 255;
    const int m0   = mt * 256;
    const int nb   = ng * 256;                    // queue row base

    const int w    = tid >> 6;
    const int lane = tid & 63;
    const int quad = lane >> 4;
    const int l16  = lane & 15;
    const int wrow = w * 64;                      // wave owns 64 M rows

    // ---- A: 64x128 bf16 per wave, straight into registers ----
    short8 a[4][4];
    #pragma unroll
    for (int mi = 0; mi < 4; ++mi)
        #pragma unroll
        for (int kk = 0; kk < 4; ++kk)
            a[mi][kk] = *(const short8*)&abf[(m0 + wrow + mi * 16 + l16) * 128
                                             + (kk * 4 + quad) * 8];

    auto issueB = [&](int t) {
        unsigned short* buf = &Bs[t & 1][0];
        const unsigned short* base = qbf + (nb + t * 64) * 128;
        #pragma unroll
        for (int r = 0; r < 4; ++r) {
            const int slot = r * 256 + w * 64 + lane;
            const int row  = slot >> 4;
            const int c    = (slot & 15) ^ (row & 15);
            __builtin_amdgcn_global_load_lds((AS1 void*)(base + row * 128 + c * 8),
                (AS3 void*)&buf[(r * 256 + w * 64) * 8], 16, 0, 0);
        }
    };
    issueB(0);
    issueB(1);

    float rs[4][4];
    #pragma unroll
    for (int mi = 0; mi < 4; ++mi)
        #pragma unroll
        for (int r = 0; r < 4; ++r) rs[mi][r] = 0.0f;

    #pragma unroll 1
    for (int t = 0; t < 4; ++t) {
        if (t < 3) __builtin_amdgcn_s_waitcnt(0x0F74);   // vmcnt(4)
        else       __builtin_amdgcn_s_waitcnt(0x0F70);   // vmcnt(0)
        __builtin_amdgcn_s_barrier();
        const unsigned short* buf = &Bs[t & 1][0];

        float4v acc[4][4];
        #pragma unroll
        for (int mi = 0; mi < 4; ++mi)
            #pragma unroll
            for (int ni = 0; ni < 4; ++ni)
                acc[mi][ni] = (float4v){0.f, 0.f, 0.f, 0.f};

        #pragma unroll
        for (int kk = 0; kk < 4; ++kk) {
            const int c = kk * 4 + quad;
            short8 b[4];
            #pragma unroll
            for (int ni = 0; ni < 4; ++ni) {
                const int row = ni * 16 + l16;
                b[ni] = *(const short8*)&buf[row * 128 + ((c ^ (row & 15)) << 3)];
            }
            #pragma unroll
            for (int mi = 0; mi < 4; ++mi)
                #pragma unroll
                for (int ni = 0; ni < 4; ++ni)
                    acc[mi][ni] = __builtin_amdgcn_mfma_f32_16x16x32_bf16(
                        a[mi][kk], b[ni], acc[mi][ni], 0, 0, 0);
        }

        // exp(10*x) = 2^(x * 10/ln2); fold into register row sums
        #pragma unroll
        for (int mi = 0; mi < 4; ++mi)
            #pragma unroll
            for (int ni = 0; ni < 4; ++ni)
                #pragma unroll
                for (int r = 0; r < 4; ++r)
                    rs[mi][r] += exp2f(acc[mi][ni][r] * 14.426950408889634f);

        if (t < 2) {
            __builtin_amdgcn_s_barrier();   // all waves done reading Bs[t&1]
            issueB(t + 2);
        }
    }

    // ---- epilogue: reduce over 16 columns, plain store per row ----
    #pragma unroll
    for (int mi = 0; mi < 4; ++mi)
        #pragma unroll
        for (int r = 0; r < 4; ++r) {
            float v = rs[mi][r];
            v += __shfl_xor(v, 1);
            v += __shfl_xor(v, 2);
            v += __shfl_xor(v, 4);
            v += __shfl_xor(v, 8);
            if (l16 == 0) rowsum[wrow + mi * 16 + quad * 4 + r] = v;
        }
    __syncthreads();
    gbuf[(m0 + tid) * 256 + ng] = rowsum[tid];
}

// Fused reduce + loss. 1 block x 1024 threads. Thread t: row r=t>>1, half
// h=t&1, sums gbuf[r*256 + h*128 .. +128) (32 float4, contiguous), pairs
// combine via shfl.
__global__ __launch_bounds__(1024) void finalize_fused_kernel(
        const float* __restrict__ pos,
        const float* __restrict__ gbuf,
        float* __restrict__ out) {
    __shared__ float wsum[16];
    __shared__ float Sp[2];
    const int tid  = threadIdx.x;
    const int w    = tid >> 6;
    const int lane = tid & 63;

    // Phase 1: Sp[j] = sum_b exp(pos[j*256+b])  (waves 0..7 hold pos data)
    float e = (tid < 512) ? __expf(pos[tid]) : 0.0f;
    #pragma unroll
    for (int off = 32; off; off >>= 1) e += __shfl_xor(e, off);
    if (lane == 0) wsum[w] = e;
    __syncthreads();
    if (tid == 0) {
        Sp[0] = wsum[0] + wsum[1] + wsum[2] + wsum[3];
        Sp[1] = wsum[4] + wsum[5] + wsum[6] + wsum[7];
    }
    __syncthreads();

    // Phase 2: Sq[r] = sum_{ng} gbuf[r*256+ng]
    const int r = tid >> 1;
    const int h = tid & 1;
    const float4* g = (const float4*)(gbuf + r * 256 + h * 128);
    float s = 0.0f;
    #pragma unroll
    for (int i = 0; i < 32; ++i) {
        const float4 v = g[i];
        s += (v.x + v.y) + (v.z + v.w);
    }
    s += __shfl_xor(s, 1);                         // both halves -> full row sum

    // Phase 3: loss
    float contrib = 0.0f;
    if (h == 0) contrib = pos[r] - __logf(Sp[r >> 8] + s);
    #pragma unroll
    for (int off = 32; off; off >>= 1) contrib += __shfl_xor(contrib, off);
    __syncthreads();                               // wsum reuse safe
    if (lane == 0) wsum[w] = contrib;
    __syncthreads();
    if (tid == 0) {
        float tot = 0.0f;
        #pragma unroll
        for (int i = 0; i < 16; ++i) tot += wsum[i];
        out[0] = -tot / 256.0f;
    }
}

// ======================================================= fallback path ====

__global__ void prep_kernel(const float* __restrict__ V,
                            const float* __restrict__ L,
                            float* __restrict__ pos,
                            float* __restrict__ Sq) {
    const int blk  = blockIdx.x;
    const int tid  = threadIdx.x;
    if (tid < 8) Sq[blk * 8 + tid] = 0.0f;
    const int w    = tid >> 6;
    const int lane = tid & 63;
    #pragma unroll
    for (int i = 0; i < 2; ++i) {
        const int r = blk * 8 + w * 2 + i;
        const int b = r & 255;
        const float2 v = *reinterpret_cast<const float2*>(V + r * 128 + lane * 2);
        const float2 l = *reinterpret_cast<const float2*>(L + b * 128 + lane * 2);
        float p = v.x * l.x + v.y * l.y;
        #pragma unroll
        for (int off = 32; off; off >>= 1) p += __shfl_xor(p, off);
        if (lane == 0) pos[r] = 10.0f * p;
    }
}

__global__ __launch_bounds__(256) void gemm_exp_fallback(
        const float* __restrict__ V,
        const float* __restrict__ Q,
        float* __restrict__ Sq) {
    __shared__ unsigned short As[128 * 128];
    __shared__ unsigned short Bs[128 * 128];
    const int tid = threadIdx.x;
    const int m0  = blockIdx.y * 128;
    const int n0  = blockIdx.x * 128;
    #pragma unroll
    for (int i = 0; i < 16; ++i) {
        const int idx = i * 256 + tid;
        const int row = idx >> 5;
        const int c4  = idx & 31;
        const float4 a = *reinterpret_cast<const float4*>(V + (m0 + row) * 128 + c4 * 4);
        const float4 b = *reinterpret_cast<const float4*>(Q + (n0 + row) * 128 + c4 * 4);
        const int chunk = ((c4 >> 1) ^ (row & 15));
        const int off   = row * 128 + (chunk << 3) + ((c4 & 1) << 2);
        const uint2 pa = make_uint2((unsigned)f2bf(a.x) | ((unsigned)f2bf(a.y) << 16),
                                    (unsigned)f2bf(a.z) | ((unsigned)f2bf(a.w) << 16));
        const uint2 pb = make_uint2((unsigned)f2bf(b.x) | ((unsigned)f2bf(b.y) << 16),
                                    (unsigned)f2bf(b.z) | ((unsigned)f2bf(b.w) << 16));
        *reinterpret_cast<uint2*>(&As[off]) = pa;
        *reinterpret_cast<uint2*>(&Bs[off]) = pb;
    }
    __syncthreads();
    const int w    = tid >> 6;
    const int lane = tid & 63;
    const int quad = lane >> 4;
    const int l16  = lane & 15;
    const int wrow = (w >> 1) * 64;
    const int wcol = (w & 1) * 64;
    float4v acc[4][4];
    #pragma unroll
    for (int mi = 0; mi < 4; ++mi)
        #pragma unroll
        for (int ni = 0; ni < 4; ++ni)
            acc[mi][ni] = (float4v){0.f, 0.f, 0.f, 0.f};
    #pragma unroll
    for (int kk = 0; kk < 4; ++kk) {
        const int kchunk = kk * 4 + quad;
        short8 a[4], b[4];
        #pragma unroll
        for (int mi = 0; mi < 4; ++mi) {
            const int row = wrow + mi * 16 + l16;
            a[mi] = *reinterpret_cast<const short8*>(&As[row * 128 + ((kchunk ^ (row & 15)) << 3)]);
        }
        #pragma unroll
        for (int ni = 0; ni < 4; ++ni) {
            const int row = wcol + ni * 16 + l16;
            b[ni] = *reinterpret_cast<const short8*>(&Bs[row * 128 + ((kchunk ^ (row & 15)) << 3)]);
        }
        #pragma unroll
        for (int mi = 0; mi < 4; ++mi)
            #pragma unroll
            for (int ni = 0; ni < 4; ++ni)
                acc[mi][ni] = __builtin_amdgcn_mfma_f32_16x16x32_bf16(a[mi], b[ni], acc[mi][ni], 0, 0, 0);
    }
    __syncthreads();
    float* rowsum = reinterpret_cast<float*>(As);
    #pragma unroll
    for (int mi = 0; mi < 4; ++mi) {
        float rsv[4] = {0.f, 0.f, 0.f, 0.f};
        #pragma unroll
        for (int ni = 0; ni < 4; ++ni)
            #pragma unroll
            for (int r = 0; r < 4; ++r)
                rsv[r] += __expf(10.0f * acc[mi][ni][r]);
        #pragma unroll
        for (int r = 0; r < 4; ++r) {
            float vsum = rsv[r];
            vsum += __shfl_xor(vsum, 1);
            vsum += __shfl_xor(vsum, 2);
            vsum += __shfl_xor(vsum, 4);
            vsum += __shfl_xor(vsum, 8);
            if (l16 == 0)
                rowsum[(w & 1) * 128 + wrow + mi * 16 + quad * 4 + r] = vsum;
        }
    }
    __syncthreads();
    if (tid < 128)
        atomicAdd(&Sq[m0 + tid], rowsum[tid] + rowsum[128 + tid]);
}

__global__ void finalize_kernel(const float* __restrict__ pos,
                                const float* __restrict__ Sq,
                                float* __restrict__ out) {
    __shared__ float wsum[8];
    __shared__ float Sp[2];
    const int tid  = threadIdx.x;
    const int w    = tid >> 6;
    const int lane = tid & 63;
    const float p = pos[tid];
    float e = __expf(p);
    #pragma unroll
    for (int off = 32; off; off >>= 1) e += __shfl_xor(e, off);
    if (lane == 0) wsum[w] = e;
    __syncthreads();
    if (tid == 0) {
        Sp[0] = wsum[0] + wsum[1] + wsum[2] + wsum[3];
        Sp[1] = wsum[4] + wsum[5] + wsum[6] + wsum[7];
    }
    __syncthreads();
    const int j = tid >> 8;
    float contrib = p - __logf(Sp[j] + Sq[tid]);
    #pragma unroll
    for (int off = 32; off; off >>= 1) contrib += __shfl_xor(contrib, off);
    if (lane == 0) wsum[w] = contrib;
    __syncthreads();
    if (tid == 0) {
        float tot = 0.f;
        #pragma unroll
        for (int i = 0; i < 8; ++i) tot += wsum[i];
        out[0] = -tot / 256.0f;
    }
}

// ======================================================= launch ===========

extern "C" void kernel_launch(void* const* d_in, const int* in_sizes, int n_in,
                              void* d_out, int out_size, void* d_ws, size_t ws_size,
                              hipStream_t stream) {
    const float* V     = (const float*)d_in[0];   // (2,256,128)
    const float* L     = (const float*)d_in[1];   // (256,128)
    const float* queue = (const float*)d_in[2];   // (65536,128)
    float* out = (float*)d_out;

    const size_t need = (size_t)65536 * 128 * 2 + (size_t)512 * 128 * 2
                      + 512 * 4 + (size_t)512 * 256 * 4;
    if (ws_size >= need) {
        unsigned short* qbf = (unsigned short*)d_ws;
        unsigned short* abf = qbf + (size_t)65536 * 128;
        float* pos  = (float*)(abf + 512 * 128);
        float* gbuf = pos + 512;                  // 512 x 256 partials
        convert_prep_kernel<<<2048, 256, 0, stream>>>(V, L, queue, qbf, abf, pos);
        gemm_exp_kernel<<<512, 256, 0, stream>>>(abf, qbf, gbuf);
        finalize_fused_kernel<<<1, 1024, 0, stream>>>(pos, gbuf, out);
    } else {
        float* pos = (float*)d_ws;
        float* Sq  = pos + 512;
        prep_kernel<<<64, 256, 0, stream>>>(V, L, pos, Sq);
        dim3 grid(512, 4);
        gemm_exp_fallback<<<grid, 256, 0, stream>>>(V, queue, Sq);
        finalize_kernel<<<1, 512, 0, stream>>>(pos, Sq, out);
    }
}

// Round 5
// 102.784 us; speedup vs baseline: 1.1505x; 1.1505x over previous
//
#include <hip/hip_runtime.h>

// ContrastiveQueueLoss: V (2,256,128) f32, L (256,128) f32, queue (65536,128) f32
// loss = -(1/256) * sum_{m<512} ( pos[m] - log( Spos[j(m)] + Sq[m] ) )

typedef float  float4v __attribute__((ext_vector_type(4)));
typedef short  short8  __attribute__((ext_vector_type(8)));

__device__ __forceinline__ unsigned short f2bf(float f) {
    union { float f; unsigned u; } v; v.f = f;
    unsigned r = v.u + 0x7FFFu + ((v.u >> 16) & 1u);   // RNE (inputs finite)
    return (unsigned short)(r >> 16);
}

// ======================================================= fast path =========

// 128 blocks x 256. Blocks 0..63: V -> bf16 (abf). Blocks 64..127: pos[512].
__global__ __launch_bounds__(256) void prep2_kernel(
        const float* __restrict__ V, const float* __restrict__ L,
        unsigned short* __restrict__ abf, float* __restrict__ pos) {
    const int tid = threadIdx.x;
    if (blockIdx.x < 64) {
        const int gt = blockIdx.x * 256 + tid;        // 16384 float4s
        const float4 v = ((const float4*)V)[gt];
        uint2 p;
        p.x = (unsigned)f2bf(v.x) | ((unsigned)f2bf(v.y) << 16);
        p.y = (unsigned)f2bf(v.z) | ((unsigned)f2bf(v.w) << 16);
        ((uint2*)abf)[gt] = p;
    } else {
        const int blk  = blockIdx.x - 64;
        const int w    = tid >> 6;
        const int lane = tid & 63;
        #pragma unroll
        for (int i = 0; i < 2; ++i) {
            const int r = blk * 8 + w * 2 + i;        // row in [0,512)
            const int b = r & 255;
            const float2 v = *reinterpret_cast<const float2*>(V + r * 128 + lane * 2);
            const float2 l = *reinterpret_cast<const float2*>(L + b * 128 + lane * 2);
            float p = v.x * l.x + v.y * l.y;
            #pragma unroll
            for (int off = 32; off; off >>= 1) p += __shfl_xor(p, off);
            if (lane == 0) pos[r] = 10.0f * p;
        }
    }
}

// 512 blocks x 256 threads (2 blocks/CU). Block bid owns queue rows
// [bid*128, bid*128+128): reads them ONCE as fp32 (64KB contiguous),
// converts to bf16 into a single 32KB XOR-swizzled LDS tile, then computes
// both 256-row M tiles against it. Partial row sums exp(10*logit) are
// written contiguously to gbuf[bid*512 + m].
// LDS layout: element (row, k) at row*128 + (((k>>3) ^ (row&15))<<3) + (k&7).
__global__ __launch_bounds__(256, 2) void gemm_exp_fused_kernel(
        const unsigned short* __restrict__ abf,
        const float* __restrict__ Qf,
        float* __restrict__ gbuf) {
    __shared__ unsigned short Bs[128 * 128];      // 32 KB
    __shared__ float rowsum[256];

    const int tid  = threadIdx.x;
    const int bid  = blockIdx.x;
    const int nb   = bid * 128;                   // queue row base

    const int w    = tid >> 6;
    const int lane = tid & 63;
    const int quad = lane >> 4;
    const int l16  = lane & 15;
    const int wrow = w * 64;                      // wave owns 64 M rows / mt

    // ---- stage B: 128x128 fp32 -> bf16, swizzled ----
    #pragma unroll
    for (int i = 0; i < 16; ++i) {
        const int idx = i * 256 + tid;            // float4 index in tile
        const int row = idx >> 5;
        const int c4  = idx & 31;
        const float4 q = *reinterpret_cast<const float4*>(Qf + (nb + row) * 128 + c4 * 4);
        uint2 p;
        p.x = (unsigned)f2bf(q.x) | ((unsigned)f2bf(q.y) << 16);
        p.y = (unsigned)f2bf(q.z) | ((unsigned)f2bf(q.w) << 16);
        const int chunk = (c4 >> 1) ^ (row & 15);
        *reinterpret_cast<uint2*>(&Bs[row * 128 + (chunk << 3) + ((c4 & 1) << 2)]) = p;
    }
    __syncthreads();

    #pragma unroll 1
    for (int mt = 0; mt < 2; ++mt) {
        const int m0 = mt * 256;

        // A-frags for this mt from L2-resident abf (128 KB total, hot)
        short8 a[4][4];
        #pragma unroll
        for (int mi = 0; mi < 4; ++mi)
            #pragma unroll
            for (int kk = 0; kk < 4; ++kk)
                a[mi][kk] = *(const short8*)&abf[(m0 + wrow + mi * 16 + l16) * 128
                                                 + (kk * 4 + quad) * 8];

        float rs[4][4];
        #pragma unroll
        for (int mi = 0; mi < 4; ++mi)
            #pragma unroll
            for (int r = 0; r < 4; ++r) rs[mi][r] = 0.0f;

        #pragma unroll
        for (int sub = 0; sub < 2; ++sub) {       // 64 queue rows each
            float4v acc[4][4];
            #pragma unroll
            for (int mi = 0; mi < 4; ++mi)
                #pragma unroll
                for (int ni = 0; ni < 4; ++ni)
                    acc[mi][ni] = (float4v){0.f, 0.f, 0.f, 0.f};

            #pragma unroll
            for (int kk = 0; kk < 4; ++kk) {
                const int c = kk * 4 + quad;
                short8 b[4];
                #pragma unroll
                for (int ni = 0; ni < 4; ++ni) {
                    const int row = sub * 64 + ni * 16 + l16;
                    b[ni] = *(const short8*)&Bs[row * 128 + ((c ^ (row & 15)) << 3)];
                }
                #pragma unroll
                for (int mi = 0; mi < 4; ++mi)
                    #pragma unroll
                    for (int ni = 0; ni < 4; ++ni)
                        acc[mi][ni] = __builtin_amdgcn_mfma_f32_16x16x32_bf16(
                            a[mi][kk], b[ni], acc[mi][ni], 0, 0, 0);
            }

            // exp(10*x) = 2^(x * 10/ln2); fold into register row sums
            #pragma unroll
            for (int mi = 0; mi < 4; ++mi)
                #pragma unroll
                for (int ni = 0; ni < 4; ++ni)
                    #pragma unroll
                    for (int r = 0; r < 4; ++r)
                        rs[mi][r] += exp2f(acc[mi][ni][r] * 14.426950408889634f);
        }

        // reduce over 16 columns -> rowsum, contiguous store to gbuf
        #pragma unroll
        for (int mi = 0; mi < 4; ++mi)
            #pragma unroll
            for (int r = 0; r < 4; ++r) {
                float v = rs[mi][r];
                v += __shfl_xor(v, 1);
                v += __shfl_xor(v, 2);
                v += __shfl_xor(v, 4);
                v += __shfl_xor(v, 8);
                if (l16 == 0) rowsum[wrow + mi * 16 + quad * 4 + r] = v;
            }
        __syncthreads();
        gbuf[bid * 512 + mt * 256 + tid] = rowsum[tid];
        __syncthreads();                           // rowsum reuse for mt=1
    }
}

// 64 blocks x 256: fold 512 block-partials -> 32. Thread g: m = g&511,
// s = g>>9; gbuf2[s*512+m] = sum_{k<16} gbuf[(s*16+k)*512 + m]. Coalesced.
__global__ __launch_bounds__(256) void reduce_k_kernel(
        const float* __restrict__ gbuf, float* __restrict__ gbuf2) {
    const int g = blockIdx.x * 256 + threadIdx.x;  // 0..16383
    const int m = g & 511;
    const int s = g >> 9;
    float acc = 0.0f;
    #pragma unroll
    for (int k = 0; k < 16; ++k)
        acc += gbuf[(s * 16 + k) * 512 + m];
    gbuf2[s * 512 + m] = acc;
}

// 1 block x 1024. Thread (m = tid>>1, h = tid&1) sums 16 of the 32 partials,
// shfl-pairs to full Sq[m]; then Sp and the loss.
__global__ __launch_bounds__(1024) void finalize_fused_kernel(
        const float* __restrict__ pos,
        const float* __restrict__ gbuf2,
        float* __restrict__ out) {
    __shared__ float wsum[16];
    __shared__ float Sp[2];
    const int tid  = threadIdx.x;
    const int w    = tid >> 6;
    const int lane = tid & 63;

    // Phase 1: Sp[j] = sum_b exp(pos[j*256+b])
    float e = (tid < 512) ? __expf(pos[tid]) : 0.0f;
    #pragma unroll
    for (int off = 32; off; off >>= 1) e += __shfl_xor(e, off);
    if (lane == 0) wsum[w] = e;
    __syncthreads();
    if (tid == 0) {
        Sp[0] = wsum[0] + wsum[1] + wsum[2] + wsum[3];
        Sp[1] = wsum[4] + wsum[5] + wsum[6] + wsum[7];
    }
    __syncthreads();

    // Phase 2: Sq[m]
    const int m = tid >> 1;
    const int h = tid & 1;
    float s = 0.0f;
    #pragma unroll
    for (int k = 0; k < 16; ++k)
        s += gbuf2[(h * 16 + k) * 512 + m];
    s += __shfl_xor(s, 1);

    // Phase 3: loss
    float contrib = 0.0f;
    if (h == 0) contrib = pos[m] - __logf(Sp[m >> 8] + s);
    #pragma unroll
    for (int off = 32; off; off >>= 1) contrib += __shfl_xor(contrib, off);
    __syncthreads();
    if (lane == 0) wsum[w] = contrib;
    __syncthreads();
    if (tid == 0) {
        float tot = 0.0f;
        #pragma unroll
        for (int i = 0; i < 16; ++i) tot += wsum[i];
        out[0] = -tot / 256.0f;
    }
}

// ======================================================= fallback path ====

__global__ void prep_kernel(const float* __restrict__ V,
                            const float* __restrict__ L,
                            float* __restrict__ pos,
                            float* __restrict__ Sq) {
    const int blk  = blockIdx.x;
    const int tid  = threadIdx.x;
    if (tid < 8) Sq[blk * 8 + tid] = 0.0f;
    const int w    = tid >> 6;
    const int lane = tid & 63;
    #pragma unroll
    for (int i = 0; i < 2; ++i) {
        const int r = blk * 8 + w * 2 + i;
        const int b = r & 255;
        const float2 v = *reinterpret_cast<const float2*>(V + r * 128 + lane * 2);
        const float2 l = *reinterpret_cast<const float2*>(L + b * 128 + lane * 2);
        float p = v.x * l.x + v.y * l.y;
        #pragma unroll
        for (int off = 32; off; off >>= 1) p += __shfl_xor(p, off);
        if (lane == 0) pos[r] = 10.0f * p;
    }
}

__global__ __launch_bounds__(256) void gemm_exp_fallback(
        const float* __restrict__ V,
        const float* __restrict__ Q,
        float* __restrict__ Sq) {
    __shared__ unsigned short As[128 * 128];
    __shared__ unsigned short Bs[128 * 128];
    const int tid = threadIdx.x;
    const int m0  = blockIdx.y * 128;
    const int n0  = blockIdx.x * 128;
    #pragma unroll
    for (int i = 0; i < 16; ++i) {
        const int idx = i * 256 + tid;
        const int row = idx >> 5;
        const int c4  = idx & 31;
        const float4 a = *reinterpret_cast<const float4*>(V + (m0 + row) * 128 + c4 * 4);
        const float4 b = *reinterpret_cast<const float4*>(Q + (n0 + row) * 128 + c4 * 4);
        const int chunk = ((c4 >> 1) ^ (row & 15));
        const int off   = row * 128 + (chunk << 3) + ((c4 & 1) << 2);
        const uint2 pa = make_uint2((unsigned)f2bf(a.x) | ((unsigned)f2bf(a.y) << 16),
                                    (unsigned)f2bf(a.z) | ((unsigned)f2bf(a.w) << 16));
        const uint2 pb = make_uint2((unsigned)f2bf(b.x) | ((unsigned)f2bf(b.y) << 16),
                                    (unsigned)f2bf(b.z) | ((unsigned)f2bf(b.w) << 16));
        *reinterpret_cast<uint2*>(&As[off]) = pa;
        *reinterpret_cast<uint2*>(&Bs[off]) = pb;
    }
    __syncthreads();
    const int w    = tid >> 6;
    const int lane = tid & 63;
    const int quad = lane >> 4;
    const int l16  = lane & 15;
    const int wrow = (w >> 1) * 64;
    const int wcol = (w & 1) * 64;
    float4v acc[4][4];
    #pragma unroll
    for (int mi = 0; mi < 4; ++mi)
        #pragma unroll
        for (int ni = 0; ni < 4; ++ni)
            acc[mi][ni] = (float4v){0.f, 0.f, 0.f, 0.f};
    #pragma unroll
    for (int kk = 0; kk < 4; ++kk) {
        const int kchunk = kk * 4 + quad;
        short8 a[4], b[4];
        #pragma unroll
        for (int mi = 0; mi < 4; ++mi) {
            const int row = wrow + mi * 16 + l16;
            a[mi] = *reinterpret_cast<const short8*>(&As[row * 128 + ((kchunk ^ (row & 15)) << 3)]);
        }
        #pragma unroll
        for (int ni = 0; ni < 4; ++ni) {
            const int row = wcol + ni * 16 + l16;
            b[ni] = *reinterpret_cast<const short8*>(&Bs[row * 128 + ((kchunk ^ (row & 15)) << 3)]);
        }
        #pragma unroll
        for (int mi = 0; mi < 4; ++mi)
            #pragma unroll
            for (int ni = 0; ni < 4; ++ni)
                acc[mi][ni] = __builtin_amdgcn_mfma_f32_16x16x32_bf16(a[mi], b[ni], acc[mi][ni], 0, 0, 0);
    }
    __syncthreads();
    float* rowsum = reinterpret_cast<float*>(As);
    #pragma unroll
    for (int mi = 0; mi < 4; ++mi) {
        float rsv[4] = {0.f, 0.f, 0.f, 0.f};
        #pragma unroll
        for (int ni = 0; ni < 4; ++ni)
            #pragma unroll
            for (int r = 0; r < 4; ++r)
                rsv[r] += __expf(10.0f * acc[mi][ni][r]);
        #pragma unroll
        for (int r = 0; r < 4; ++r) {
            float vsum = rsv[r];
            vsum += __shfl_xor(vsum, 1);
            vsum += __shfl_xor(vsum, 2);
            vsum += __shfl_xor(vsum, 4);
            vsum += __shfl_xor(vsum, 8);
            if (l16 == 0)
                rowsum[(w & 1) * 128 + wrow + mi * 16 + quad * 4 + r] = vsum;
        }
    }
    __syncthreads();
    if (tid < 128)
        atomicAdd(&Sq[m0 + tid], rowsum[tid] + rowsum[128 + tid]);
}

__global__ void finalize_kernel(const float* __restrict__ pos,
                                const float* __restrict__ Sq,
                                float* __restrict__ out) {
    __shared__ float wsum[8];
    __shared__ float Sp[2];
    const int tid  = threadIdx.x;
    const int w    = tid >> 6;
    const int lane = tid & 63;
    const float p = pos[tid];
    float e = __expf(p);
    #pragma unroll
    for (int off = 32; off; off >>= 1) e += __shfl_xor(e, off);
    if (lane == 0) wsum[w] = e;
    __syncthreads();
    if (tid == 0) {
        Sp[0] = wsum[0] + wsum[1] + wsum[2] + wsum[3];
        Sp[1] = wsum[4] + wsum[5] + wsum[6] + wsum[7];
    }
    __syncthreads();
    const int j = tid >> 8;
    float contrib = p - __logf(Sp[j] + Sq[tid]);
    #pragma unroll
    for (int off = 32; off; off >>= 1) contrib += __shfl_xor(contrib, off);
    if (lane == 0) wsum[w] = contrib;
    __syncthreads();
    if (tid == 0) {
        float tot = 0.f;
        #pragma unroll
        for (int i = 0; i < 8; ++i) tot += wsum[i];
        out[0] = -tot / 256.0f;
    }
}

// ======================================================= launch ===========

extern "C" void kernel_launch(void* const* d_in, const int* in_sizes, int n_in,
                              void* d_out, int out_size, void* d_ws, size_t ws_size,
                              hipStream_t stream) {
    const float* V     = (const float*)d_in[0];   // (2,256,128)
    const float* L     = (const float*)d_in[1];   // (256,128)
    const float* queue = (const float*)d_in[2];   // (65536,128)
    float* out = (float*)d_out;

    const size_t need = (size_t)512 * 128 * 2 + 512 * 4
                      + (size_t)512 * 512 * 4 + (size_t)32 * 512 * 4;
    if (ws_size >= need) {
        unsigned short* abf = (unsigned short*)d_ws;          // 512x128 bf16
        float* pos   = (float*)(abf + 512 * 128);             // 512
        float* gbuf  = pos + 512;                             // 512x512
        float* gbuf2 = gbuf + (size_t)512 * 512;              // 32x512
        prep2_kernel<<<128, 256, 0, stream>>>(V, L, abf, pos);
        gemm_exp_fused_kernel<<<512, 256, 0, stream>>>(abf, queue, gbuf);
        reduce_k_kernel<<<64, 256, 0, stream>>>(gbuf, gbuf2);
        finalize_fused_kernel<<<1, 1024, 0, stream>>>(pos, gbuf2, out);
    } else {
        float* pos = (float*)d_ws;
        float* Sq  = pos + 512;
        prep_kernel<<<64, 256, 0, stream>>>(V, L, pos, Sq);
        dim3 grid(512, 4);
        gemm_exp_fallback<<<grid, 256, 0, stream>>>(V, queue, Sq);
        finalize_kernel<<<1, 512, 0, stream>>>(pos, Sq, out);
    }
}